// Round 1
// 1002.141 us; speedup vs baseline: 1.0633x; 1.0633x over previous
//
#include <hip/hip_runtime.h>
#include <cstdint>
#include <math.h>

#define EMB 128
#define CHUNK 32   // tokens staged per iteration (16 KB LDS, swizzled)

// starts[b] = first token index with segment_ids[i] >= b  (segment_ids sorted).
// starts[B] = T. Handles empty segments naturally.
__global__ void seg_starts_kernel(const int* __restrict__ seg, int T, int B,
                                  int* __restrict__ starts) {
    int b = blockIdx.x * blockDim.x + threadIdx.x;
    if (b > B) return;
    int lo = 0, hi = T;
    while (lo < hi) {
        int mid = (lo + hi) >> 1;
        if (seg[mid] < b) lo = mid + 1; else hi = mid;
    }
    starts[b] = lo;
}

// Layout notes:
//  - key_lds holds CHUNK rows of 512 B, XOR-swizzled: physical colbyte =
//    logical colbyte ^ ((row&7)<<4). Staged with global_load_lds (linear LDS
//    dest = uniform base + lane*16), so the swizzle is applied by inverse-
//    swizzling the per-lane GLOBAL source address (involution).
//  - scores: 8 lanes per token (lane j8 covers 16 cols), 3-step shfl_xor.
//  - softmax: computed redundantly by every wave (bitwise identical), e kept
//    in registers: lane t holds e(token t).
//  - accumulate: lane owns float4 column group c4 (lanes 0-31 + token parity
//    from lane>>5); one instruction reads two full rows coalesced.
__global__ __launch_bounds__(256, 6) void attn_kernel(
    const float* __restrict__ value, const float* __restrict__ key,
    const int* __restrict__ starts, const float* __restrict__ fingerprint,
    const float* __restrict__ w, float* __restrict__ out, int T)
{
    __shared__ __align__(16) float key_lds[CHUNK * EMB];  // 16 KB (also reused for final reduce)
    __shared__ float s_lds[CHUNK];                        // raw scores
    __shared__ __align__(16) float dwf_lds[EMB];          // diag(w)*fp/sqrt(E)

    const int b    = blockIdx.x;
    const int tid  = threadIdx.x;
    const int lane = tid & 63;
    const int wv   = tid >> 6;

    const int s0  = starts[b];
    const int s1  = starts[b + 1];
    const int len = s1 - s0;

    if (tid < EMB)
        dwf_lds[tid] = w[tid * EMB + tid] * fingerprint[tid] * 0.08838834764831845f; // 1/sqrt(128)
    __syncthreads();

    const int g8   = lane >> 3;   // score phase: token index within wave's 8
    const int j8   = lane & 7;    // score phase: 16-col slice
    const int half = lane >> 5;   // accumulate: token parity
    const int c4   = lane & 31;   // accumulate: float4 column group

    float4 dw[4];
    #pragma unroll
    for (int q = 0; q < 4; ++q)
        dw[q] = *reinterpret_cast<const float4*>(&dwf_lds[j8 * 16 + q * 4]);

    float4 vacc = make_float4(0.f, 0.f, 0.f, 0.f);
    float4 kacc = make_float4(0.f, 0.f, 0.f, 0.f);
    float m = -INFINITY, denom = 0.0f;

    const char* key_b = (const char*)key;

    for (int o = 0; o < len; o += CHUNK) {
        const int cl = min(CHUNK, len - o);

        // ---- stage key chunk: global_load_lds x4 per wave, 1 KB each ----
        // dest byte D = q*1024 + lane*16 (linear); row r = D>>9 = 2q+half;
        // source is inverse-swizzled; row clamped for tail/array-end safety
        // (clamped rows hold valid floats, later multiplied by e=0).
        #pragma unroll
        for (int i = 0; i < 4; ++i) {
            const int q  = (wv << 2) + i;          // 0..15
            const int r  = (q << 1) + half;        // 0..31
            const int gr = min(s0 + o + r, T - 1);
            const char* src = key_b + (size_t)gr * 512 + ((c4 ^ (r & 7)) << 4);
            __builtin_amdgcn_global_load_lds(
                (const __attribute__((address_space(1))) void*)src,
                (__attribute__((address_space(3))) void*)(key_lds + (q << 8)),
                16, 0, 0);
        }
        __syncthreads();   // stage visible (drains vmcnt)

        // ---- scores: 8 lanes per token, swizzled ds_read_b128 ----
        {
            const int t = (wv << 3) + g8;          // 0..31
            float sc = 0.0f;
            if (t < cl) {
                const char* rowp = (const char*)key_lds + t * 512;
                const int swz = (t & 7) << 4;
                #pragma unroll
                for (int q = 0; q < 4; ++q) {
                    const float4 k = *reinterpret_cast<const float4*>(
                        rowp + (((((j8 << 2) + q) << 4)) ^ swz));
                    sc = fmaf(k.x, dw[q].x, sc);
                    sc = fmaf(k.y, dw[q].y, sc);
                    sc = fmaf(k.z, dw[q].z, sc);
                    sc = fmaf(k.w, dw[q].w, sc);
                }
            }
            sc += __shfl_xor(sc, 1);
            sc += __shfl_xor(sc, 2);
            sc += __shfl_xor(sc, 4);
            if (j8 == 0) s_lds[t] = (t < cl) ? sc : -INFINITY;
        }
        __syncthreads();   // s_lds ready

        // ---- online softmax: every wave computes the (identical) reduction ----
        const float s = (lane < CHUNK) ? s_lds[lane] : -INFINITY;
        float mx = s;
        #pragma unroll
        for (int off = 32; off; off >>= 1) mx = fmaxf(mx, __shfl_xor(mx, off));
        const float m_new = fmaxf(m, mx);
        const float e = (s > -INFINITY) ? __expf(s - m_new) : 0.0f;  // lane t holds e(token t)
        float cs = e;
        #pragma unroll
        for (int off = 32; off; off >>= 1) cs += __shfl_xor(cs, off);
        const float alpha = (m > -INFINITY) ? __expf(m - m_new) : 0.0f;
        denom = denom * alpha + cs;
        m = m_new;
        vacc.x *= alpha; vacc.y *= alpha; vacc.z *= alpha; vacc.w *= alpha;
        kacc.x *= alpha; kacc.y *= alpha; kacc.z *= alpha; kacc.w *= alpha;

        // ---- accumulate: wave w takes token-pairs p = w, w+4, w+8, w+12 ----
        // lanes 0-31 = row 2p cols, lanes 32-63 = row 2p+1 cols, float4 each:
        // one global instr reads 1 KB (two value rows), one ds_read_b128 the
        // matching key rows (swizzled, conflict-free). e broadcast via shfl.
        const float4* vrow4 = (const float4*)(value + (size_t)(s0 + o) * EMB);
        #pragma unroll
        for (int pp = 0; pp < 4; ++pp) {
            const int t  = ((wv + (pp << 2)) << 1) + half;   // 0..31
            const int tc = min(t, cl - 1);                   // safe addr; e=0 masks tail
            const float et = __shfl(e, t);
            const float4 v = vrow4[(size_t)tc * 32 + c4];
            const float4 kk = *reinterpret_cast<const float4*>(
                (const char*)key_lds + tc * 512 + ((c4 ^ (tc & 7)) << 4));
            vacc.x = fmaf(et, v.x, vacc.x);
            vacc.y = fmaf(et, v.y, vacc.y);
            vacc.z = fmaf(et, v.z, vacc.z);
            vacc.w = fmaf(et, v.w, vacc.w);
            kacc.x = fmaf(et, kk.x, kacc.x);
            kacc.y = fmaf(et, kk.y, kacc.y);
            kacc.z = fmaf(et, kk.z, kacc.z);
            kacc.w = fmaf(et, kk.w, kacc.w);
        }
        __syncthreads();   // key_lds free before next stage overwrites
    }

    // ---- combine token-parity halves (lanes l and l^32 hold disjoint partials) ----
    vacc.x += __shfl_xor(vacc.x, 32);
    vacc.y += __shfl_xor(vacc.y, 32);
    vacc.z += __shfl_xor(vacc.z, 32);
    vacc.w += __shfl_xor(vacc.w, 32);
    kacc.x += __shfl_xor(kacc.x, 32);
    kacc.y += __shfl_xor(kacc.y, 32);
    kacc.z += __shfl_xor(kacc.z, 32);
    kacc.w += __shfl_xor(kacc.w, 32);

    // ---- cross-wave reduce through key_lds (reused as 4x256-float scratch) ----
    if (lane < 32) {
        float4* dst = reinterpret_cast<float4*>(key_lds);
        dst[(wv << 6) + c4]      = vacc;   // value cols at [wv*256 + 0..127]
        dst[(wv << 6) + 32 + c4] = kacc;   // key   cols at [wv*256 + 128..255]
    }
    __syncthreads();

    const float sum = key_lds[tid] + key_lds[256 + tid]
                    + key_lds[512 + tid] + key_lds[768 + tid];
    const float r = (denom > 0.0f) ? sum / denom : 0.0f;
    out[(size_t)b * (2 * EMB) + tid] = r;
}

extern "C" void kernel_launch(void* const* d_in, const int* in_sizes, int n_in,
                              void* d_out, int out_size, void* d_ws, size_t ws_size,
                              hipStream_t stream) {
    const float* value = (const float*)d_in[0];
    const float* key   = (const float*)d_in[1];
    const int*   seg   = (const int*)d_in[2];
    const float* fp    = (const float*)d_in[3];
    const float* w     = (const float*)d_in[4];
    float* out = (float*)d_out;

    const int T = in_sizes[2];
    const int B = out_size / (2 * EMB);

    int* starts = (int*)d_ws;  // (B+1) ints, recomputed every call (ws is poisoned)

    const int nb = (B + 1 + 255) / 256;
    seg_starts_kernel<<<nb, 256, 0, stream>>>(seg, T, B, starts);
    attn_kernel<<<B, 256, 0, stream>>>(value, key, starts, fp, w, out, T);
}